// Round 8
// baseline (328.157 us; speedup 1.0000x reference)
//
#include <hip/hip_runtime.h>
#include <hip/hip_bf16.h>
#include <hip/hip_cooperative_groups.h>
#include <cstdint>
#include <cstddef>

namespace cg = cooperative_groups;

// Problem constants
#define B_   2
#define L_   2048
#define IN_  128
#define H_   512
#define OUT_ 64
#define NL_  2
#define ED_  1024
#define N_   16
#define DR_  32
#define K_   4

static constexpr int M_TOK = B_ * L_;   // 4096 tokens
static constexpr int SEG   = 64;        // scan segments
static constexpr int TS    = L_ / SEG;  // 32 steps per segment

typedef __attribute__((ext_vector_type(8))) short bhalf8;   // 8 bf16 (4 VGPRs)
typedef __attribute__((ext_vector_type(4))) float floatx4;  // MFMA accumulator

__device__ __forceinline__ ushort bf16bits(float f)
{
    __hip_bfloat16 h = __float2bfloat16(f);
    return *reinterpret_cast<ushort*>(&h);
}

// direct global->LDS 16B/lane (dest = wave-uniform base + lane*16)
__device__ __forceinline__ void gld_lds16(const ushort* g, ushort* l)
{
    __builtin_amdgcn_global_load_lds(
        (const __attribute__((address_space(1))) unsigned int*)g,
        (__attribute__((address_space(3))) unsigned int*)l, 16, 0, 0);
}

// ---------------------------------------------------------------------------
// bf16 MFMA GEMM: C[M,N] = epi(A[M,K] @ B[K,N]), B supplied TRANSPOSED [N][K].
// EPI: 0 plain f32, 1 C+=v, 2 tanh(v+b1+b2)->bf16, 3 v+b1->f32,
//      4 split-K partial C[kz*M*N+row*N+col]=v, 5 w=v+b1; out=w-tanh(w),
//      6 softplus(v+b1)->f32, 7 w=C+v; C=w and Cb=bf16(w)
// DUAL: grid.z=2 selects (Bt,C) vs (Bt2,C2), same A.
// ---------------------------------------------------------------------------
template<int BM, int BN, int BK, int EPI, bool DUAL>
__global__ __launch_bounds__(256)
void mfma_gemm(const ushort* __restrict__ A, int lda,
               const ushort* Bt, int ldb,
               const ushort* Bt2, float* C2,
               const float* __restrict__ b1, const float* __restrict__ b2,
               float* C, __hip_bfloat16* Cb, int ldc,
               int M, int N, int kc)
{
    __shared__ __align__(16) ushort As[BM * BK];
    __shared__ __align__(16) ushort Bs[BN * BK];

    const int tid  = threadIdx.x;
    const int bm   = blockIdx.x * BM, bn = blockIdx.y * BN;
    int kz = 0, kbeg = 0;
    if (DUAL) {
        if (blockIdx.z) { Bt = Bt2; C = C2; }
    } else {
        kz = blockIdx.z; kbeg = kz * kc;
    }
    const int lane = tid & 63, wave = tid >> 6;
    const int wr = wave >> 1, wc = wave & 1;
    constexpr int WM = BM / 2, WN = BN / 2;
    constexpr int FM = WM / 16, FN = WN / 16;
    const int fr = lane & 15, fg = lane >> 4;

    constexpr int ACH = BM * BK / 512;
    constexpr int BCH = BN * BK / 512;
    constexpr int RPC = 512 / BK;
    constexpr int LPR = BK / 8;
    const int sr = lane / LPR;
    const int sc = (lane % LPR) * 8;

    floatx4 acc[FM][FN] = {};

    for (int k0 = kbeg; k0 < kbeg + kc; k0 += BK) {
        #pragma unroll
        for (int i = 0; i < ACH / 4; ++i) {
            const int ci = wave * (ACH / 4) + i;
            const int r  = ci * RPC + sr;
            gld_lds16(&A[(size_t)(bm + r) * lda + k0 + sc], &As[ci * 512]);
        }
        #pragma unroll
        for (int i = 0; i < BCH / 4; ++i) {
            const int ci = wave * (BCH / 4) + i;
            const int r  = ci * RPC + sr;
            gld_lds16(&Bt[(size_t)(bn + r) * ldb + k0 + sc], &Bs[ci * 512]);
        }
        __syncthreads();
        #pragma unroll
        for (int kk = 0; kk < BK; kk += 32) {
            bhalf8 fa[FM], fb[FN];
            #pragma unroll
            for (int m = 0; m < FM; ++m)
                fa[m] = *reinterpret_cast<const bhalf8*>(
                    &As[(wr * WM + m * 16 + fr) * BK + kk + fg * 8]);
            #pragma unroll
            for (int n = 0; n < FN; ++n)
                fb[n] = *reinterpret_cast<const bhalf8*>(
                    &Bs[(wc * WN + n * 16 + fr) * BK + kk + fg * 8]);
            #pragma unroll
            for (int m = 0; m < FM; ++m)
                #pragma unroll
                for (int n = 0; n < FN; ++n)
                    acc[m][n] = __builtin_amdgcn_mfma_f32_16x16x32_bf16(
                        fa[m], fb[n], acc[m][n], 0, 0, 0);
        }
        __syncthreads();
    }

    #pragma unroll
    for (int m = 0; m < FM; ++m) {
        #pragma unroll
        for (int n = 0; n < FN; ++n) {
            const int row0 = bm + wr * WM + m * 16 + fg * 4;
            const int col  = bn + wc * WN + n * 16 + fr;
            #pragma unroll
            for (int r = 0; r < 4; ++r) {
                float v = acc[m][n][r];
                const int row = row0 + r;
                if (EPI == 0) {
                    C[(size_t)row * ldc + col] = v;
                } else if (EPI == 1) {
                    C[(size_t)row * ldc + col] += v;
                } else if (EPI == 2) {
                    Cb[(size_t)row * ldc + col] =
                        __float2bfloat16(tanhf(v + b1[col] + b2[col]));
                } else if (EPI == 3) {
                    C[(size_t)row * ldc + col] = v + b1[col];
                } else if (EPI == 4) {
                    C[(size_t)kz * M * N + (size_t)row * N + col] = v;
                } else if (EPI == 5) {
                    const float w = v + b1[col];
                    C[(size_t)row * ldc + col] = w - tanhf(w);
                } else if (EPI == 6) {
                    const float w = v + b1[col];
                    C[(size_t)row * ldc + col] =
                        fmaxf(w, 0.0f) + log1pf(expf(-fabsf(w)));
                } else if (EPI == 7) {
                    float* cp = C + (size_t)row * ldc + col;
                    const float w = *cp + v;
                    *cp = w;
                    Cb[(size_t)row * ldc + col] = __float2bfloat16(w);
                }
            }
        }
    }
}

// ---------------------------------------------------------------------------
// xproj GEMM with conv+silu fused into A-staging.
// ---------------------------------------------------------------------------
__global__ __launch_bounds__(256)
void xproj_gemm(const float* __restrict__ xcr,
                const float* __restrict__ cw, const float* __restrict__ cb,
                const ushort* __restrict__ Bt,    // [64][1024]
                float* __restrict__ Cpart)        // [8][M_TOK][64]
{
    __shared__ __align__(16) ushort As[128 * 64];
    __shared__ __align__(16) ushort Bs[64 * 64];

    const int tid = threadIdx.x;
    const int bm  = blockIdx.x * 128;
    const int kz  = blockIdx.z;
    const int lane = tid & 63, wave = tid >> 6;
    const int wr = wave >> 1, wc = wave & 1;
    const int fr = lane & 15, fg = lane >> 4;
    const int tseq0 = bm & (L_ - 1);

    const int col8 = (tid & 7) * 8;
    const int rq   = tid >> 3;
    const int sr   = lane / 8, sc2 = (lane & 7) * 8;

    floatx4 acc[4][2] = {};

    #pragma unroll
    for (int ks = 0; ks < 2; ++ks) {
        const int k0 = kz * 128 + ks * 64;

        float4 wv[8]; float cbv[8];
        #pragma unroll
        for (int j = 0; j < 8; ++j) {
            wv[j]  = *reinterpret_cast<const float4*>(&cw[(k0 + col8 + j) * 4]);
            cbv[j] = cb[k0 + col8 + j];
        }
        float xr[7][8];
        #pragma unroll
        for (int ii = 0; ii < 7; ++ii) {
            const int tok = bm + rq * 4 - 3 + ii;
            const int tokc = tok < 0 ? 0 : tok;
            const float4 a = *reinterpret_cast<const float4*>(
                &xcr[(size_t)tokc * ED_ + k0 + col8]);
            const float4 b = *reinterpret_cast<const float4*>(
                &xcr[(size_t)tokc * ED_ + k0 + col8 + 4]);
            xr[ii][0]=a.x; xr[ii][1]=a.y; xr[ii][2]=a.z; xr[ii][3]=a.w;
            xr[ii][4]=b.x; xr[ii][5]=b.y; xr[ii][6]=b.z; xr[ii][7]=b.w;
        }
        #pragma unroll
        for (int rr = 0; rr < 4; ++rr) {
            const int trow = tseq0 + rq * 4 + rr;
            __align__(16) ushort ob[8];
            #pragma unroll
            for (int j = 0; j < 8; ++j) {
                float a = cbv[j] + wv[j].w * xr[rr + 3][j];
                if (trow >= 1) a += wv[j].z * xr[rr + 2][j];
                if (trow >= 2) a += wv[j].y * xr[rr + 1][j];
                if (trow >= 3) a += wv[j].x * xr[rr + 0][j];
                const float s = a / (1.0f + __expf(-a));
                ob[j] = bf16bits(s);
            }
            *reinterpret_cast<uint4*>(&As[(rq * 4 + rr) * 64 + col8]) =
                *reinterpret_cast<const uint4*>(ob);
        }
        #pragma unroll
        for (int i = 0; i < 2; ++i) {
            const int ci = wave * 2 + i;
            const int r  = ci * 8 + sr;
            gld_lds16(&Bt[(size_t)r * ED_ + k0 + sc2], &Bs[ci * 512]);
        }
        __syncthreads();
        #pragma unroll
        for (int kk = 0; kk < 64; kk += 32) {
            bhalf8 fa[4], fb[2];
            #pragma unroll
            for (int m = 0; m < 4; ++m)
                fa[m] = *reinterpret_cast<const bhalf8*>(
                    &As[(wr * 64 + m * 16 + fr) * 64 + kk + fg * 8]);
            #pragma unroll
            for (int n = 0; n < 2; ++n)
                fb[n] = *reinterpret_cast<const bhalf8*>(
                    &Bs[(wc * 32 + n * 16 + fr) * 64 + kk + fg * 8]);
            #pragma unroll
            for (int m = 0; m < 4; ++m)
                #pragma unroll
                for (int n = 0; n < 2; ++n)
                    acc[m][n] = __builtin_amdgcn_mfma_f32_16x16x32_bf16(
                        fa[m], fb[n], acc[m][n], 0, 0, 0);
        }
        __syncthreads();
    }

    #pragma unroll
    for (int m = 0; m < 4; ++m) {
        #pragma unroll
        for (int n = 0; n < 2; ++n) {
            const int row0 = bm + wr * 64 + m * 16 + fg * 4;
            const int col  = wc * 32 + n * 16 + fr;
            #pragma unroll
            for (int r = 0; r < 4; ++r)
                Cpart[(size_t)kz * M_TOK * 64 + (size_t)(row0 + r) * 64 + col] =
                    acc[m][n][r];
        }
    }
}

// split-K reduce; OUTMODE: 0=f32, 1=bf16, 2=both
template<int NP, int ACT, bool B1, bool B2, int OUTMODE>
__global__ __launch_bounds__(256)
void reduce_part_k(const float* __restrict__ P, const float* __restrict__ b1,
                   const float* __restrict__ b2, float* __restrict__ Of,
                   __hip_bfloat16* __restrict__ Ob, int MN, int Ncols)
{
    const int i = blockIdx.x * 256 + threadIdx.x;
    float s = 0.0f;
    #pragma unroll
    for (int z = 0; z < NP; ++z) s += P[(size_t)z * MN + i];
    const int col = i & (Ncols - 1);
    if (B1) s += b1[col];
    if (B2) s += b2[col];
    if (ACT == 1) s = tanhf(s);
    if (OUTMODE == 0 || OUTMODE == 2) Of[i] = s;
    if (OUTMODE == 1 || OUTMODE == 2) Ob[i] = __float2bfloat16(s);
}

// ---------------------------------------------------------------------------
// prep mega-kernel
// ---------------------------------------------------------------------------
__device__ __forceinline__ void tr32(float (*t)[33],
                                     const float* __restrict__ W,
                                     __hip_bfloat16* __restrict__ Wt,
                                     int K, int N, int local, int gx, int tid)
{
    const int kx = local % gx, ny = local / gx;
    const int k0 = kx * 32, n0 = ny * 32;
    const int c = tid & 31, r4 = tid >> 5;
    #pragma unroll
    for (int i = 0; i < 4; ++i) {
        const int rr = r4 + i * 8;
        t[rr][c] = W[(size_t)(k0 + rr) * N + n0 + c];
    }
    __syncthreads();
    #pragma unroll
    for (int i = 0; i < 4; ++i) {
        const int rr = r4 + i * 8;
        Wt[(size_t)(n0 + rr) * K + k0 + c] = __float2bfloat16(t[c][rr]);
    }
}

__global__ __launch_bounds__(256)
void prep_k(const float* __restrict__ x, __hip_bfloat16* __restrict__ Xb,
            const float* pWi, __hip_bfloat16* TpWi,
            const float* pWo, __hip_bfloat16* TpWo,
            const float* inW, __hip_bfloat16* TinW0, __hip_bfloat16* TinW1,
            const float* xpW, __hip_bfloat16* TxpW0, __hip_bfloat16* TxpW1,
            const float* outW, __hip_bfloat16* ToutW0, __hip_bfloat16* ToutW1,
            const float* dWi, __hip_bfloat16* TdWi,
            const float* dtW, __hip_bfloat16* TdtW0, __hip_bfloat16* TdtW1,
            const float* dWo, __hip_bfloat16* TdWo)
{
    __shared__ float t[32][33];
    const int tid = threadIdx.x;
    int r = blockIdx.x;

    if (r < 512) {
        const int i = (r * 256 + tid) * 4;
        const float4 v = *reinterpret_cast<const float4*>(&x[i]);
        ushort4 u;
        u.x = bf16bits(v.x); u.y = bf16bits(v.y);
        u.z = bf16bits(v.z); u.w = bf16bits(v.w);
        *reinterpret_cast<ushort4*>(&Xb[i]) = u;
        return;
    }
    r -= 512;
    if (r < 64)   { tr32(t, pWi, TpWi, IN_, H_, r, 4, tid); return; }   r -= 64;
    if (r < 256)  { tr32(t, pWo, TpWo, H_, H_, r, 16, tid); return; }   r -= 256;
    if (r < 1024) { tr32(t, inW, TinW0, H_, 2 * ED_, r, 16, tid); return; } r -= 1024;
    if (r < 1024) { tr32(t, inW + (size_t)H_ * 2 * ED_, TinW1, H_, 2 * ED_, r, 16, tid); return; } r -= 1024;
    if (r < 64)   { tr32(t, xpW, TxpW0, ED_, 64, r, 32, tid); return; } r -= 64;
    if (r < 64)   { tr32(t, xpW + (size_t)ED_ * 64, TxpW1, ED_, 64, r, 32, tid); return; } r -= 64;
    if (r < 512)  { tr32(t, outW, ToutW0, ED_, H_, r, 32, tid); return; } r -= 512;
    if (r < 512)  { tr32(t, outW + (size_t)ED_ * H_, ToutW1, ED_, H_, r, 32, tid); return; } r -= 512;
    if (r < 32)   { tr32(t, dWi, TdWi, H_, OUT_, r, 16, tid); return; } r -= 32;
    if (r < 32)   { tr32(t, dtW, TdtW0, DR_, ED_, r, 1, tid); return; } r -= 32;
    if (r < 32)   { tr32(t, dtW + DR_ * ED_, TdtW1, DR_, ED_, r, 1, tid); return; } r -= 32;
    tr32(t, dWo, TdWo, OUT_, OUT_, r, 2, tid);
}
static constexpr int PREP_BLOCKS = 512 + 64 + 256 + 1024 + 1024 + 64 + 64 + 512 + 512 + 32 + 32 + 32 + 4;

// ---------------------------------------------------------------------------
// RMSNorm over H=512 -> bf16 out
// ---------------------------------------------------------------------------
__global__ __launch_bounds__(256)
void rmsnorm_k(const float* __restrict__ x, const float* __restrict__ w,
               __hip_bfloat16* __restrict__ o)
{
    const int row = blockIdx.x;
    const int tid = threadIdx.x;
    const float* xr = x + (size_t)row * H_;
    float v0 = xr[tid], v1 = xr[tid + 256];
    float s = v0 * v0 + v1 * v1;
    #pragma unroll
    for (int off = 32; off > 0; off >>= 1) s += __shfl_down(s, off, 64);
    __shared__ float ps[4];
    __shared__ float scale_s;
    const int wave = tid >> 6, lane = tid & 63;
    if (lane == 0) ps[wave] = s;
    __syncthreads();
    if (tid == 0) {
        float tot = ps[0] + ps[1] + ps[2] + ps[3];
        scale_s = rsqrtf(tot * (1.0f / H_) + 1e-5f);
    }
    __syncthreads();
    const float sc = scale_s;
    o[(size_t)row * H_ + tid]       = __float2bfloat16(v0 * sc * w[tid]);
    o[(size_t)row * H_ + tid + 256] = __float2bfloat16(v1 * sc * w[tid + 256]);
}

// ---------------------------------------------------------------------------
// COOPERATIVE mega-scan: stage once -> P1 -> grid.sync -> combine ->
// grid.sync -> P3 reusing LDS staging. Grid MUST be 2048 x 256.
// LDS 20480 B x 8 blocks/CU = 160 KiB exactly; VGPR capped at 64 via bounds.
// ---------------------------------------------------------------------------
__global__ __launch_bounds__(256, 8)
void ssm_mega_k(const float* __restrict__ delta,
                const float* __restrict__ xcr,
                const float* __restrict__ dbl,
                const float* __restrict__ cw, const float* __restrict__ cb,
                const float* __restrict__ zbuf,
                const float* __restrict__ A_log,
                const float* __restrict__ Dv,
                float* __restrict__ hend, float* __restrict__ pprod,
                float* __restrict__ hinit,
                __hip_bfloat16* __restrict__ ybuf)
{
    __shared__ float sdl[TS][64];
    __shared__ float sxc[TS][64];
    __shared__ float bc[TS][32];

    const int bx   = blockIdx.x;
    const int seg  = bx & (SEG - 1);
    const int dblk = (bx >> 6) & 15;
    const int b    = bx >> 10;
    const int tid  = threadIdx.x;
    const int dbase = dblk * 64;
    const int t0   = seg * TS;
    const size_t row0 = (size_t)(b * L_ + t0);
    const int dls = tid & 63;

    // ---- staging (once) ----
    #pragma unroll
    for (int e = 0; e < 8; ++e) {
        const int t = (tid >> 6) + e * 4;
        sdl[t][dls] = delta[(row0 + t) * ED_ + dbase + dls];
    }
    {
        const int tg = tid >> 6;
        const int tb = tg * 8;
        float xr[11];
        #pragma unroll
        for (int ii = 0; ii < 11; ++ii) {
            const int gt = t0 + tb - 3 + ii;
            xr[ii] = (gt >= 0)
                ? xcr[((size_t)(b * L_) + gt) * ED_ + dbase + dls] : 0.0f;
        }
        const float4 w = *reinterpret_cast<const float4*>(&cw[(dbase + dls) * 4]);
        const float cbv = cb[dbase + dls];
        #pragma unroll
        for (int k = 0; k < 8; ++k) {
            const float a = cbv + w.x * xr[k] + w.y * xr[k + 1]
                          + w.z * xr[k + 2] + w.w * xr[k + 3];
            sxc[tb + k][dls] = a / (1.0f + __expf(-a));
        }
    }
    #pragma unroll
    for (int e = 0; e < 4; ++e) {
        const int lin = tid + e * 256;
        bc[lin >> 5][lin & 31] = dbl[(row0 + (lin >> 5)) * 64 + 32 + (lin & 31)];
    }
    __syncthreads();

    const int dl = tid >> 2;
    const int ng = tid & 3;
    const int d  = dbase + dl;

    float Av[4];
    #pragma unroll
    for (int i = 0; i < 4; ++i) Av[i] = -expf(A_log[d * N_ + ng * 4 + i]);
    const float Dd = Dv[d];

    // ---- P1: zero-init recurrence ----
    {
        float h[4] = {0.0f, 0.0f, 0.0f, 0.0f};
        float S = 0.0f;
        #pragma unroll
        for (int t = 0; t < TS; ++t) {
            const float dvt = sdl[t][dl];
            const float dx  = dvt * sxc[t][dl];
            S += dvt;
            #pragma unroll
            for (int i = 0; i < 4; ++i) {
                const float dA = __expf(dvt * Av[i]);
                h[i] = fmaf(dA, h[i], dx * bc[t][ng * 4 + i]);
            }
        }
        #pragma unroll
        for (int i = 0; i < 4; ++i) {
            const size_t o = ((size_t)(b * SEG + seg) * N_ + ng * 4 + i) * ED_ + d;
            hend[o]  = h[i];
            pprod[o] = __expf(Av[i] * S);
        }
    }

    cg::this_grid().sync();

    // ---- combine (first 128 blocks = 32768 threads over (b,n,d)) ----
    if (bx < 128) {
        const int gid = bx * 256 + tid;
        const int dd = gid & (ED_ - 1);
        const int nn = (gid >> 10) & (N_ - 1);
        const int bb = gid >> 14;
        size_t o = ((size_t)(bb * SEG) * N_ + nn) * ED_ + dd;
        const size_t stride = (size_t)N_ * ED_;
        float hh = 0.0f;
        #pragma unroll 8
        for (int s = 0; s < SEG; ++s) {
            hinit[o] = hh;
            hh = fmaf(pprod[o], hh, hend[o]);
            o += stride;
        }
    }

    cg::this_grid().sync();

    // ---- P3: true-init recurrence + output (LDS staging still valid) ----
    {
        float h[4];
        #pragma unroll
        for (int i = 0; i < 4; ++i)
            h[i] = hinit[((size_t)(b * SEG + seg) * N_ + ng * 4 + i) * ED_ + d];
        #pragma unroll
        for (int t = 0; t < TS; ++t) {
            const float dvt = sdl[t][dl];
            const float xvt = sxc[t][dl];
            const float dx  = dvt * xvt;
            float ysum = 0.0f;
            #pragma unroll
            for (int i = 0; i < 4; ++i) {
                const float dA = __expf(dvt * Av[i]);
                h[i] = fmaf(dA, h[i], dx * bc[t][ng * 4 + i]);
                ysum = fmaf(h[i], bc[t][16 + ng * 4 + i], ysum);
            }
            float y2 = ysum + __shfl_xor(ysum, 1, 64);
            float y4 = y2 + __shfl_xor(y2, 2, 64);
            if (ng == 0) {
                const float zv = zbuf[(row0 + t) * ED_ + d];
                const float sz = zv / (1.0f + __expf(-zv));
                ybuf[(row0 + t) * ED_ + d] =
                    __float2bfloat16((y4 + Dd * xvt) * sz);
            }
        }
    }
}

// ---------------------------------------------------------------------------
// Legacy fallback scan kernels (bit-identical math) if coop launch unavailable
// ---------------------------------------------------------------------------
template<bool P3>
__global__ __launch_bounds__(256)
void ssm_scan_k(const float* __restrict__ delta,
                const float* __restrict__ xcr,
                const float* __restrict__ dbl,
                const float* __restrict__ cw, const float* __restrict__ cb,
                const float* __restrict__ zbuf,
                const float* __restrict__ A_log,
                const float* __restrict__ Dv,
                float* __restrict__ hend, float* __restrict__ pprod,
                const float* __restrict__ hinit,
                __hip_bfloat16* __restrict__ ybuf)
{
    __shared__ float sdl[TS][64];
    __shared__ float sxc[TS][64];
    __shared__ float bc[TS][32];

    const int bx   = blockIdx.x;
    const int seg  = bx & (SEG - 1);
    const int dblk = (bx >> 6) & 15;
    const int b    = bx >> 10;
    const int tid  = threadIdx.x;
    const int dbase = dblk * 64;
    const int t0   = seg * TS;
    const size_t row0 = (size_t)(b * L_ + t0);
    const int dls = tid & 63;

    #pragma unroll
    for (int e = 0; e < 8; ++e) {
        const int t = (tid >> 6) + e * 4;
        sdl[t][dls] = delta[(row0 + t) * ED_ + dbase + dls];
    }
    {
        const int tg = tid >> 6;
        const int tb = tg * 8;
        float xr[11];
        #pragma unroll
        for (int ii = 0; ii < 11; ++ii) {
            const int gt = t0 + tb - 3 + ii;
            xr[ii] = (gt >= 0)
                ? xcr[((size_t)(b * L_) + gt) * ED_ + dbase + dls] : 0.0f;
        }
        const float4 w = *reinterpret_cast<const float4*>(&cw[(dbase + dls) * 4]);
        const float cbv = cb[dbase + dls];
        #pragma unroll
        for (int k = 0; k < 8; ++k) {
            const float a = cbv + w.x * xr[k] + w.y * xr[k + 1]
                          + w.z * xr[k + 2] + w.w * xr[k + 3];
            sxc[tb + k][dls] = a / (1.0f + __expf(-a));
        }
    }
    #pragma unroll
    for (int e = 0; e < 4; ++e) {
        const int lin = tid + e * 256;
        bc[lin >> 5][lin & 31] = dbl[(row0 + (lin >> 5)) * 64 + 32 + (lin & 31)];
    }
    __syncthreads();

    const int dl = tid >> 2;
    const int ng = tid & 3;
    const int d  = dbase + dl;

    float Av[4];
    #pragma unroll
    for (int i = 0; i < 4; ++i) Av[i] = -expf(A_log[d * N_ + ng * 4 + i]);

    float h[4];
    float S = 0.0f;
    if (P3) {
        #pragma unroll
        for (int i = 0; i < 4; ++i)
            h[i] = hinit[((size_t)(b * SEG + seg) * N_ + ng * 4 + i) * ED_ + d];
    } else {
        #pragma unroll
        for (int i = 0; i < 4; ++i) h[i] = 0.0f;
    }
    const float Dd = P3 ? Dv[d] : 0.0f;

    #pragma unroll
    for (int t = 0; t < TS; ++t) {
        const float dvt = sdl[t][dl];
        const float xvt = sxc[t][dl];
        const float dx  = dvt * xvt;
        if (!P3) S += dvt;
        float ysum = 0.0f;
        #pragma unroll
        for (int i = 0; i < 4; ++i) {
            const float dA = __expf(dvt * Av[i]);
            h[i] = fmaf(dA, h[i], dx * bc[t][ng * 4 + i]);
            if (P3) ysum = fmaf(h[i], bc[t][16 + ng * 4 + i], ysum);
        }
        if (P3) {
            float y2 = ysum + __shfl_xor(ysum, 1, 64);
            float y4 = y2 + __shfl_xor(y2, 2, 64);
            if (ng == 0) {
                const float zv = zbuf[(row0 + t) * ED_ + d];
                const float sz = zv / (1.0f + __expf(-zv));
                ybuf[(row0 + t) * ED_ + d] =
                    __float2bfloat16((y4 + Dd * xvt) * sz);
            }
        }
    }

    if (!P3) {
        #pragma unroll
        for (int i = 0; i < 4; ++i) {
            const size_t o = ((size_t)(b * SEG + seg) * N_ + ng * 4 + i) * ED_ + d;
            hend[o]  = h[i];
            pprod[o] = __expf(Av[i] * S);
        }
    }
}

__global__ __launch_bounds__(256)
void ssm_combine_k(const float* __restrict__ hend, const float* __restrict__ pprod,
                   float* __restrict__ hinit)
{
    const int gid = blockIdx.x * 256 + threadIdx.x;
    const int d = gid & (ED_ - 1);
    const int n = (gid >> 10) & (N_ - 1);
    const int b = gid >> 14;
    size_t o = ((size_t)(b * SEG) * N_ + n) * ED_ + d;
    const size_t stride = (size_t)N_ * ED_;
    float h = 0.0f;
    #pragma unroll 8
    for (int s = 0; s < SEG; ++s) {
        hinit[o] = h;
        h = fmaf(pprod[o], h, hend[o]);
        o += stride;
    }
}

// ---------------------------------------------------------------------------
extern "C" void kernel_launch(void* const* d_in, const int* in_sizes, int n_in,
                              void* d_out, int out_size, void* d_ws, size_t ws_size,
                              hipStream_t stream)
{
    const float* x      = (const float*)d_in[0];
    const float* p_Wi   = (const float*)d_in[1];
    const float* p_bi   = (const float*)d_in[2];
    const float* p_bh   = (const float*)d_in[3];
    const float* p_Wo   = (const float*)d_in[4];
    const float* p_bo   = (const float*)d_in[5];
    const float* m_norm = (const float*)d_in[6];
    const float* m_inW  = (const float*)d_in[7];
    const float* m_cw   = (const float*)d_in[8];
    const float* m_cb   = (const float*)d_in[9];
    const float* m_xpW  = (const float*)d_in[10];
    const float* m_dtW  = (const float*)d_in[11];
    const float* m_dtb  = (const float*)d_in[12];
    const float* m_Alog = (const float*)d_in[13];
    const float* m_D    = (const float*)d_in[14];
    const float* m_outW = (const float*)d_in[15];
    const float* d_Wi   = (const float*)d_in[16];
    const float* d_bi   = (const float*)d_in[17];
    const float* d_bh   = (const float*)d_in[18];
    const float* d_Wo   = (const float*)d_in[19];
    const float* d_bo   = (const float*)d_in[20];
    float* out_f = (float*)d_out;
    float* ws = (float*)d_ws;

    // ---- workspace layout (floats) ----
    float* OUT   = ws;                 //  2,097,152
    float* XCR   = ws + 2097152;       //  4,194,304  inW out; later CPART2
    float* Z     = ws + 6291456;       //  4,194,304
    float* DELTA = ws + 10485760;      //  4,194,304
    float* HEND  = ws + 14680064;      //  2,097,152  (first: xproj partials)
    float* PPROD = ws + 16777216;      //  2,097,152  (later: OUTb)
    float* HINIT = ws + 18874368;      //  2,097,152
    float* BF    = ws + 20971520;      //  2,097,152  bf16 activations
    float* WT    = ws + 23068672;      //  1,853,440  bf16 transposed weights
    float* DBL   = ws + 24922112;      //    262,144  (later: H2b)
    float* DBLF  = ws + 25184256;      //    131,072  bf16 dbl copy

    // aliases
    float* CPARTX = HEND;
    float* CPART2 = XCR;
    __hip_bfloat16* Xb   = (__hip_bfloat16*)BF;
    __hip_bfloat16* H1b  = (__hip_bfloat16*)(BF + 262144);
    __hip_bfloat16* XNb  = (__hip_bfloat16*)BF;
    __hip_bfloat16* YB   = (__hip_bfloat16*)BF;
    __hip_bfloat16* H2b  = (__hip_bfloat16*)DBL;
    __hip_bfloat16* OUTb = (__hip_bfloat16*)PPROD;
    __hip_bfloat16* DBLb = (__hip_bfloat16*)DBLF;

    __hip_bfloat16* WTu     = (__hip_bfloat16*)WT;
    __hip_bfloat16* T_pWi   = WTu;            // [512][128]
    __hip_bfloat16* T_pWo   = WTu + 65536;    // [512][512]
    __hip_bfloat16* T_inW0  = WTu + 327680;   // [2048][512]
    __hip_bfloat16* T_inW1  = WTu + 1376256;
    __hip_bfloat16* T_xpW0  = WTu + 2424832;  // [64][1024]
    __hip_bfloat16* T_xpW1  = WTu + 2490368;
    __hip_bfloat16* T_outW0 = WTu + 2555904;  // [512][1024]
    __hip_bfloat16* T_outW1 = WTu + 3080192;
    __hip_bfloat16* T_dWi   = WTu + 3604480;  // [64][512]
    __hip_bfloat16* T_dtW0  = WTu + 3637248;  // [1024][32]
    __hip_bfloat16* T_dtW1  = WTu + 3670016;
    __hip_bfloat16* T_dWo   = WTu + 3702784;  // [64][64]

    const dim3 blk(256);

    // cooperative-launch availability check (host-side, deterministic,
    // capture-safe: no stream ops, no allocations)
    int coop_ok = 0;
    {
        int dev = 0, attr = 0;
        if (hipGetDevice(&dev) == hipSuccess &&
            hipDeviceGetAttribute(&attr, hipDeviceAttributeCooperativeLaunch,
                                  dev) == hipSuccess && attr) {
            int nb = 0;
            if (hipOccupancyMaxActiveBlocksPerMultiprocessor(
                    &nb, ssm_mega_k, 256, 0) == hipSuccess && nb >= 8)
                coop_ok = 1;
        }
    }

    // ---- all weight conversions + x cvt in one launch ----
    prep_k<<<dim3(PREP_BLOCKS), blk, 0, stream>>>(
        x, Xb, p_Wi, T_pWi, p_Wo, T_pWo, m_inW, T_inW0, T_inW1,
        m_xpW, T_xpW0, T_xpW1, m_outW, T_outW0, T_outW1,
        d_Wi, T_dWi, m_dtW, T_dtW0, T_dtW1, d_Wo, T_dWo);

    // ---- liquid1 ----
    mfma_gemm<128, 64, 64, 2, false><<<dim3(32, 8), blk, 0, stream>>>(
        (const ushort*)Xb, IN_, (const ushort*)T_pWi, IN_, nullptr, nullptr,
        p_bi, p_bh, nullptr, H1b, H_, M_TOK, H_, IN_);
    mfma_gemm<128, 64, 64, 3, false><<<dim3(32, 8), blk, 0, stream>>>(
        (const ushort*)H1b, H_, (const ushort*)T_pWo, H_, nullptr, nullptr,
        p_bo, nullptr, OUT, nullptr, H_, M_TOK, H_, H_);

    for (int l = 0; l < NL_; ++l) {
        const float* nw   = m_norm + l * H_;
        const float* cw   = m_cw   + l * ED_ * K_;
        const float* cb   = m_cb   + l * ED_;
        const float* dtb  = m_dtb  + l * ED_;
        const float* Alog = m_Alog + l * ED_ * N_;
        const float* Dv   = m_D    + l * ED_;
        const __hip_bfloat16* TinW  = l ? T_inW1  : T_inW0;
        const __hip_bfloat16* TxpW  = l ? T_xpW1  : T_xpW0;
        const __hip_bfloat16* ToutW = l ? T_outW1 : T_outW0;
        const __hip_bfloat16* TdtW  = l ? T_dtW1  : T_dtW0;

        rmsnorm_k<<<dim3(M_TOK), blk, 0, stream>>>(OUT, nw, XNb);
        mfma_gemm<128, 128, 64, 0, true><<<dim3(32, 8, 2), blk, 0, stream>>>(
            (const ushort*)XNb, H_, (const ushort*)TinW, H_,
            (const ushort*)(TinW + (size_t)ED_ * H_), Z,
            nullptr, nullptr, XCR, nullptr, ED_, M_TOK, ED_, H_);
        xproj_gemm<<<dim3(32, 1, 8), blk, 0, stream>>>(
            XCR, cw, cb, (const ushort*)TxpW, CPARTX);
        reduce_part_k<8, 0, false, false, 2><<<dim3(1024), blk, 0, stream>>>(
            CPARTX, nullptr, nullptr, DBL, DBLb, M_TOK * 64, 64);
        mfma_gemm<128, 64, 32, 6, false><<<dim3(32, 16), blk, 0, stream>>>(
            (const ushort*)DBLb, 64, (const ushort*)TdtW, DR_, nullptr, nullptr,
            dtb, nullptr, DELTA, nullptr, ED_, M_TOK, ED_, DR_);

        if (coop_ok) {
            const float* a0 = DELTA;  const float* a1 = XCR;
            const float* a2 = DBL;    const float* a3 = cw;
            const float* a4 = cb;     const float* a5 = Z;
            const float* a6 = Alog;   const float* a7 = Dv;
            float* a8 = HEND;  float* a9 = PPROD;  float* a10 = HINIT;
            __hip_bfloat16* a11 = YB;
            void* args[12] = {&a0, &a1, &a2, &a3, &a4, &a5,
                              &a6, &a7, &a8, &a9, &a10, &a11};
            hipLaunchCooperativeKernel((void*)ssm_mega_k, dim3(2048), blk,
                                       args, 0, stream);
        } else {
            ssm_scan_k<false><<<dim3(2048), blk, 0, stream>>>(
                DELTA, XCR, DBL, cw, cb, nullptr, Alog, nullptr,
                HEND, PPROD, nullptr, nullptr);
            ssm_combine_k<<<dim3(128), blk, 0, stream>>>(HEND, PPROD, HINIT);
            ssm_scan_k<true><<<dim3(2048), blk, 0, stream>>>(
                DELTA, XCR, DBL, cw, cb, Z, Alog, Dv,
                nullptr, nullptr, HINIT, YB);
        }

        if (l == 0) {
            mfma_gemm<128, 64, 64, 1, false><<<dim3(32, 8), blk, 0, stream>>>(
                (const ushort*)YB, ED_, (const ushort*)ToutW, ED_, nullptr, nullptr,
                nullptr, nullptr, OUT, nullptr, H_, M_TOK, H_, ED_);
        } else {
            mfma_gemm<128, 64, 64, 7, false><<<dim3(32, 8), blk, 0, stream>>>(
                (const ushort*)YB, ED_, (const ushort*)ToutW, ED_, nullptr, nullptr,
                nullptr, nullptr, OUT, OUTb, H_, M_TOK, H_, ED_);
        }
    }

    // ---- liquid2 + final (fused v - tanh(v)) ----
    mfma_gemm<128, 64, 64, 4, false><<<dim3(32, 1, 8), blk, 0, stream>>>(
        (const ushort*)OUTb, H_, (const ushort*)T_dWi, H_, nullptr, nullptr,
        nullptr, nullptr, CPART2, nullptr, 64, M_TOK, 64, H_ / 8);
    reduce_part_k<8, 1, true, true, 1><<<dim3(1024), blk, 0, stream>>>(
        CPART2, d_bi, d_bh, nullptr, H2b, M_TOK * 64, 64);
    mfma_gemm<128, 64, 64, 5, false><<<dim3(32, 1), blk, 0, stream>>>(
        (const ushort*)H2b, OUT_, (const ushort*)T_dWo, OUT_, nullptr, nullptr,
        d_bo, nullptr, out_f, nullptr, OUT_, M_TOK, OUT_, OUT_);
}

// Round 9
// 321.066 us; speedup vs baseline: 1.0221x; 1.0221x over previous
//
#include <hip/hip_runtime.h>
#include <hip/hip_bf16.h>
#include <cstdint>
#include <cstddef>

// Problem constants
#define B_   2
#define L_   2048
#define IN_  128
#define H_   512
#define OUT_ 64
#define NL_  2
#define ED_  1024
#define N_   16
#define DR_  32
#define K_   4

static constexpr int M_TOK = B_ * L_;   // 4096 tokens
static constexpr int SEG   = 64;        // scan segments
static constexpr int TS    = L_ / SEG;  // 32 steps per segment

typedef __attribute__((ext_vector_type(8))) short bhalf8;   // 8 bf16 (4 VGPRs)
typedef __attribute__((ext_vector_type(4))) float floatx4;  // MFMA accumulator

__device__ __forceinline__ ushort bf16bits(float f)
{
    __hip_bfloat16 h = __float2bfloat16(f);
    return *reinterpret_cast<ushort*>(&h);
}
__device__ __forceinline__ float b2f(ushort u)
{
    union { uint32_t i; float f; } x;
    x.i = ((uint32_t)u) << 16;
    return x.f;
}

// direct global->LDS 16B/lane (dest = wave-uniform base + lane*16)
__device__ __forceinline__ void gld_lds16(const ushort* g, ushort* l)
{
    __builtin_amdgcn_global_load_lds(
        (const __attribute__((address_space(1))) unsigned int*)g,
        (__attribute__((address_space(3))) unsigned int*)l, 16, 0, 0);
}

// ---------------------------------------------------------------------------
// bf16 MFMA GEMM: C[M,N] = epi(A[M,K] @ B[K,N]), B supplied TRANSPOSED [N][K].
// EPI: 0 plain f32, 1 C+=v, 2 tanh(v+b1+b2)->bf16, 3 v+b1->f32,
//      4 split-K partial C[kz*M*N+row*N+col]=v, 5 w=v+b1; out=w-tanh(w),
//      7 w=C+v; C=w and Cb=bf16(w), 8 Cb=bf16(v), 9 Cb=bf16(softplus(v+b1))
// DUAL: grid.z=2 selects (Bt,C,Cb) vs (Bt2,C2,Cb2), same A.
// ---------------------------------------------------------------------------
template<int BM, int BN, int BK, int EPI, bool DUAL>
__global__ __launch_bounds__(256)
void mfma_gemm(const ushort* __restrict__ A, int lda,
               const ushort* Bt, int ldb,
               const ushort* Bt2, float* C2, __hip_bfloat16* Cb2,
               const float* __restrict__ b1, const float* __restrict__ b2,
               float* C, __hip_bfloat16* Cb, int ldc,
               int M, int N, int kc)
{
    __shared__ __align__(16) ushort As[BM * BK];
    __shared__ __align__(16) ushort Bs[BN * BK];

    const int tid  = threadIdx.x;
    const int bm   = blockIdx.x * BM, bn = blockIdx.y * BN;
    int kz = 0, kbeg = 0;
    if (DUAL) {
        if (blockIdx.z) { Bt = Bt2; C = C2; Cb = Cb2; }
    } else {
        kz = blockIdx.z; kbeg = kz * kc;
    }
    const int lane = tid & 63, wave = tid >> 6;
    const int wr = wave >> 1, wc = wave & 1;
    constexpr int WM = BM / 2, WN = BN / 2;
    constexpr int FM = WM / 16, FN = WN / 16;
    const int fr = lane & 15, fg = lane >> 4;

    constexpr int ACH = BM * BK / 512;
    constexpr int BCH = BN * BK / 512;
    constexpr int RPC = 512 / BK;
    constexpr int LPR = BK / 8;
    const int sr = lane / LPR;
    const int sc = (lane % LPR) * 8;

    floatx4 acc[FM][FN] = {};

    for (int k0 = kbeg; k0 < kbeg + kc; k0 += BK) {
        #pragma unroll
        for (int i = 0; i < ACH / 4; ++i) {
            const int ci = wave * (ACH / 4) + i;
            const int r  = ci * RPC + sr;
            gld_lds16(&A[(size_t)(bm + r) * lda + k0 + sc], &As[ci * 512]);
        }
        #pragma unroll
        for (int i = 0; i < BCH / 4; ++i) {
            const int ci = wave * (BCH / 4) + i;
            const int r  = ci * RPC + sr;
            gld_lds16(&Bt[(size_t)(bn + r) * ldb + k0 + sc], &Bs[ci * 512]);
        }
        __syncthreads();
        #pragma unroll
        for (int kk = 0; kk < BK; kk += 32) {
            bhalf8 fa[FM], fb[FN];
            #pragma unroll
            for (int m = 0; m < FM; ++m)
                fa[m] = *reinterpret_cast<const bhalf8*>(
                    &As[(wr * WM + m * 16 + fr) * BK + kk + fg * 8]);
            #pragma unroll
            for (int n = 0; n < FN; ++n)
                fb[n] = *reinterpret_cast<const bhalf8*>(
                    &Bs[(wc * WN + n * 16 + fr) * BK + kk + fg * 8]);
            #pragma unroll
            for (int m = 0; m < FM; ++m)
                #pragma unroll
                for (int n = 0; n < FN; ++n)
                    acc[m][n] = __builtin_amdgcn_mfma_f32_16x16x32_bf16(
                        fa[m], fb[n], acc[m][n], 0, 0, 0);
        }
        __syncthreads();
    }

    #pragma unroll
    for (int m = 0; m < FM; ++m) {
        #pragma unroll
        for (int n = 0; n < FN; ++n) {
            const int row0 = bm + wr * WM + m * 16 + fg * 4;
            const int col  = bn + wc * WN + n * 16 + fr;
            #pragma unroll
            for (int r = 0; r < 4; ++r) {
                float v = acc[m][n][r];
                const int row = row0 + r;
                if (EPI == 0) {
                    C[(size_t)row * ldc + col] = v;
                } else if (EPI == 1) {
                    C[(size_t)row * ldc + col] += v;
                } else if (EPI == 2) {
                    Cb[(size_t)row * ldc + col] =
                        __float2bfloat16(tanhf(v + b1[col] + b2[col]));
                } else if (EPI == 3) {
                    C[(size_t)row * ldc + col] = v + b1[col];
                } else if (EPI == 4) {
                    C[(size_t)kz * M * N + (size_t)row * N + col] = v;
                } else if (EPI == 5) {
                    const float w = v + b1[col];
                    C[(size_t)row * ldc + col] = w - tanhf(w);
                } else if (EPI == 7) {
                    float* cp = C + (size_t)row * ldc + col;
                    const float w = *cp + v;
                    *cp = w;
                    Cb[(size_t)row * ldc + col] = __float2bfloat16(w);
                } else if (EPI == 8) {
                    Cb[(size_t)row * ldc + col] = __float2bfloat16(v);
                } else if (EPI == 9) {
                    const float w = v + b1[col];
                    const float sp = fmaxf(w, 0.0f) + log1pf(expf(-fabsf(w)));
                    Cb[(size_t)row * ldc + col] = __float2bfloat16(sp);
                }
            }
        }
    }
}

// ---------------------------------------------------------------------------
// xproj GEMM with conv+silu fused into A-staging; xcr input is bf16.
// ---------------------------------------------------------------------------
__global__ __launch_bounds__(256)
void xproj_gemm(const ushort* __restrict__ xcrb,
                const float* __restrict__ cw, const float* __restrict__ cb,
                const ushort* __restrict__ Bt,    // [64][1024]
                float* __restrict__ Cpart)        // [8][M_TOK][64]
{
    __shared__ __align__(16) ushort As[128 * 64];
    __shared__ __align__(16) ushort Bs[64 * 64];

    const int tid = threadIdx.x;
    const int bm  = blockIdx.x * 128;
    const int kz  = blockIdx.z;
    const int lane = tid & 63, wave = tid >> 6;
    const int wr = wave >> 1, wc = wave & 1;
    const int fr = lane & 15, fg = lane >> 4;
    const int tseq0 = bm & (L_ - 1);

    const int col8 = (tid & 7) * 8;
    const int rq   = tid >> 3;
    const int sr   = lane / 8, sc2 = (lane & 7) * 8;

    floatx4 acc[4][2] = {};

    #pragma unroll
    for (int ks = 0; ks < 2; ++ks) {
        const int k0 = kz * 128 + ks * 64;

        float4 wv[8]; float cbv[8];
        #pragma unroll
        for (int j = 0; j < 8; ++j) {
            wv[j]  = *reinterpret_cast<const float4*>(&cw[(k0 + col8 + j) * 4]);
            cbv[j] = cb[k0 + col8 + j];
        }
        float xr[7][8];
        #pragma unroll
        for (int ii = 0; ii < 7; ++ii) {
            const int tok = bm + rq * 4 - 3 + ii;
            const int tokc = tok < 0 ? 0 : tok;
            const bhalf8 v = *reinterpret_cast<const bhalf8*>(
                &xcrb[(size_t)tokc * ED_ + k0 + col8]);
            #pragma unroll
            for (int j = 0; j < 8; ++j) xr[ii][j] = b2f((ushort)v[j]);
        }
        #pragma unroll
        for (int rr = 0; rr < 4; ++rr) {
            const int trow = tseq0 + rq * 4 + rr;
            __align__(16) ushort ob[8];
            #pragma unroll
            for (int j = 0; j < 8; ++j) {
                float a = cbv[j] + wv[j].w * xr[rr + 3][j];
                if (trow >= 1) a += wv[j].z * xr[rr + 2][j];
                if (trow >= 2) a += wv[j].y * xr[rr + 1][j];
                if (trow >= 3) a += wv[j].x * xr[rr + 0][j];
                const float s = a / (1.0f + __expf(-a));
                ob[j] = bf16bits(s);
            }
            *reinterpret_cast<uint4*>(&As[(rq * 4 + rr) * 64 + col8]) =
                *reinterpret_cast<const uint4*>(ob);
        }
        #pragma unroll
        for (int i = 0; i < 2; ++i) {
            const int ci = wave * 2 + i;
            const int r  = ci * 8 + sr;
            gld_lds16(&Bt[(size_t)r * ED_ + k0 + sc2], &Bs[ci * 512]);
        }
        __syncthreads();
        #pragma unroll
        for (int kk = 0; kk < 64; kk += 32) {
            bhalf8 fa[4], fb[2];
            #pragma unroll
            for (int m = 0; m < 4; ++m)
                fa[m] = *reinterpret_cast<const bhalf8*>(
                    &As[(wr * 64 + m * 16 + fr) * 64 + kk + fg * 8]);
            #pragma unroll
            for (int n = 0; n < 2; ++n)
                fb[n] = *reinterpret_cast<const bhalf8*>(
                    &Bs[(wc * 32 + n * 16 + fr) * 64 + kk + fg * 8]);
            #pragma unroll
            for (int m = 0; m < 4; ++m)
                #pragma unroll
                for (int n = 0; n < 2; ++n)
                    acc[m][n] = __builtin_amdgcn_mfma_f32_16x16x32_bf16(
                        fa[m], fb[n], acc[m][n], 0, 0, 0);
        }
        __syncthreads();
    }

    #pragma unroll
    for (int m = 0; m < 4; ++m) {
        #pragma unroll
        for (int n = 0; n < 2; ++n) {
            const int row0 = bm + wr * 64 + m * 16 + fg * 4;
            const int col  = wc * 32 + n * 16 + fr;
            #pragma unroll
            for (int r = 0; r < 4; ++r)
                Cpart[(size_t)kz * M_TOK * 64 + (size_t)(row0 + r) * 64 + col] =
                    acc[m][n][r];
        }
    }
}

// split-K reduce; OUTMODE: 0=f32, 1=bf16, 2=both
template<int NP, int ACT, bool B1, bool B2, int OUTMODE>
__global__ __launch_bounds__(256)
void reduce_part_k(const float* __restrict__ P, const float* __restrict__ b1,
                   const float* __restrict__ b2, float* __restrict__ Of,
                   __hip_bfloat16* __restrict__ Ob, int MN, int Ncols)
{
    const int i = blockIdx.x * 256 + threadIdx.x;
    float s = 0.0f;
    #pragma unroll
    for (int z = 0; z < NP; ++z) s += P[(size_t)z * MN + i];
    const int col = i & (Ncols - 1);
    if (B1) s += b1[col];
    if (B2) s += b2[col];
    if (ACT == 1) s = tanhf(s);
    if (OUTMODE == 0 || OUTMODE == 2) Of[i] = s;
    if (OUTMODE == 1 || OUTMODE == 2) Ob[i] = __float2bfloat16(s);
}

// ---------------------------------------------------------------------------
// prep mega-kernel: x->bf16 cvt + all weight transpose-converts, one launch.
// ---------------------------------------------------------------------------
__device__ __forceinline__ void tr32(float (*t)[33],
                                     const float* __restrict__ W,
                                     __hip_bfloat16* __restrict__ Wt,
                                     int K, int N, int local, int gx, int tid)
{
    const int kx = local % gx, ny = local / gx;
    const int k0 = kx * 32, n0 = ny * 32;
    const int c = tid & 31, r4 = tid >> 5;
    #pragma unroll
    for (int i = 0; i < 4; ++i) {
        const int rr = r4 + i * 8;
        t[rr][c] = W[(size_t)(k0 + rr) * N + n0 + c];
    }
    __syncthreads();
    #pragma unroll
    for (int i = 0; i < 4; ++i) {
        const int rr = r4 + i * 8;
        Wt[(size_t)(n0 + rr) * K + k0 + c] = __float2bfloat16(t[c][rr]);
    }
}

__global__ __launch_bounds__(256)
void prep_k(const float* __restrict__ x, __hip_bfloat16* __restrict__ Xb,
            const float* pWi, __hip_bfloat16* TpWi,
            const float* pWo, __hip_bfloat16* TpWo,
            const float* inW, __hip_bfloat16* TinW0, __hip_bfloat16* TinW1,
            const float* xpW, __hip_bfloat16* TxpW0, __hip_bfloat16* TxpW1,
            const float* outW, __hip_bfloat16* ToutW0, __hip_bfloat16* ToutW1,
            const float* dWi, __hip_bfloat16* TdWi,
            const float* dtW, __hip_bfloat16* TdtW0, __hip_bfloat16* TdtW1,
            const float* dWo, __hip_bfloat16* TdWo)
{
    __shared__ float t[32][33];
    const int tid = threadIdx.x;
    int r = blockIdx.x;

    if (r < 512) {
        const int i = (r * 256 + tid) * 4;
        const float4 v = *reinterpret_cast<const float4*>(&x[i]);
        ushort4 u;
        u.x = bf16bits(v.x); u.y = bf16bits(v.y);
        u.z = bf16bits(v.z); u.w = bf16bits(v.w);
        *reinterpret_cast<ushort4*>(&Xb[i]) = u;
        return;
    }
    r -= 512;
    if (r < 64)   { tr32(t, pWi, TpWi, IN_, H_, r, 4, tid); return; }   r -= 64;
    if (r < 256)  { tr32(t, pWo, TpWo, H_, H_, r, 16, tid); return; }   r -= 256;
    if (r < 1024) { tr32(t, inW, TinW0, H_, 2 * ED_, r, 16, tid); return; } r -= 1024;
    if (r < 1024) { tr32(t, inW + (size_t)H_ * 2 * ED_, TinW1, H_, 2 * ED_, r, 16, tid); return; } r -= 1024;
    if (r < 64)   { tr32(t, xpW, TxpW0, ED_, 64, r, 32, tid); return; } r -= 64;
    if (r < 64)   { tr32(t, xpW + (size_t)ED_ * 64, TxpW1, ED_, 64, r, 32, tid); return; } r -= 64;
    if (r < 512)  { tr32(t, outW, ToutW0, ED_, H_, r, 32, tid); return; } r -= 512;
    if (r < 512)  { tr32(t, outW + (size_t)ED_ * H_, ToutW1, ED_, H_, r, 32, tid); return; } r -= 512;
    if (r < 32)   { tr32(t, dWi, TdWi, H_, OUT_, r, 16, tid); return; } r -= 32;
    if (r < 32)   { tr32(t, dtW, TdtW0, DR_, ED_, r, 1, tid); return; } r -= 32;
    if (r < 32)   { tr32(t, dtW + DR_ * ED_, TdtW1, DR_, ED_, r, 1, tid); return; } r -= 32;
    tr32(t, dWo, TdWo, OUT_, OUT_, r, 2, tid);
}
static constexpr int PREP_BLOCKS = 512 + 64 + 256 + 1024 + 1024 + 64 + 64 + 512 + 512 + 32 + 32 + 32 + 4;

// ---------------------------------------------------------------------------
// RMSNorm over H=512 -> bf16 out
// ---------------------------------------------------------------------------
__global__ __launch_bounds__(256)
void rmsnorm_k(const float* __restrict__ x, const float* __restrict__ w,
               __hip_bfloat16* __restrict__ o)
{
    const int row = blockIdx.x;
    const int tid = threadIdx.x;
    const float* xr = x + (size_t)row * H_;
    float v0 = xr[tid], v1 = xr[tid + 256];
    float s = v0 * v0 + v1 * v1;
    #pragma unroll
    for (int off = 32; off > 0; off >>= 1) s += __shfl_down(s, off, 64);
    __shared__ float ps[4];
    __shared__ float scale_s;
    const int wave = tid >> 6, lane = tid & 63;
    if (lane == 0) ps[wave] = s;
    __syncthreads();
    if (tid == 0) {
        float tot = ps[0] + ps[1] + ps[2] + ps[3];
        scale_s = rsqrtf(tot * (1.0f / H_) + 1e-5f);
    }
    __syncthreads();
    const float sc = scale_s;
    o[(size_t)row * H_ + tid]       = __float2bfloat16(v0 * sc * w[tid]);
    o[(size_t)row * H_ + tid + 256] = __float2bfloat16(v1 * sc * w[tid + 256]);
}

// ---------------------------------------------------------------------------
// SSM chunked scan; bf16 delta/xcr/z inputs, register-staged conv+silu.
// Block 256 thr; LDS 20 KB; grid B*SEG*(ED/64) = 2048 blocks.
// ---------------------------------------------------------------------------
template<bool P3>
__global__ __launch_bounds__(256)
void ssm_scan_k(const ushort* __restrict__ deltab,  // (M_TOK, ED) bf16
                const ushort* __restrict__ xcrb,    // (M_TOK, ED) bf16 pre-conv
                const float* __restrict__ dbl,      // (M_TOK, 64) f32
                const float* __restrict__ cw, const float* __restrict__ cb,
                const ushort* __restrict__ zb,      // (M_TOK, ED) bf16
                const float* __restrict__ A_log,
                const float* __restrict__ Dv,
                float* __restrict__ hend, float* __restrict__ pprod,
                const float* __restrict__ hinit,
                __hip_bfloat16* __restrict__ ybuf)
{
    __shared__ float sdl[TS][64];
    __shared__ float sxc[TS][64];
    __shared__ float bc[TS][32];

    const int bx   = blockIdx.x;
    const int seg  = bx & (SEG - 1);
    const int dblk = (bx >> 6) & 15;
    const int b    = bx >> 10;
    const int tid  = threadIdx.x;
    const int dbase = dblk * 64;
    const int t0   = seg * TS;
    const size_t row0 = (size_t)(b * L_ + t0);
    const int dls = tid & 63;

    // delta staging: one vectorized pass (256 thr x 8 bf16 = 2048 elems)
    {
        const int rowt = tid >> 3;
        const int d8   = (tid & 7) * 8;
        const bhalf8 v = *reinterpret_cast<const bhalf8*>(
            &deltab[(row0 + rowt) * ED_ + dbase + d8]);
        #pragma unroll
        for (int j = 0; j < 8; ++j) sdl[rowt][d8 + j] = b2f((ushort)v[j]);
    }
    // conv+silu staging: thread group tg handles t-run tg*8..+7 at channel dls
    {
        const int tg = tid >> 6;
        const int tb = tg * 8;
        float xr[11];
        #pragma unroll
        for (int ii = 0; ii < 11; ++ii) {
            const int gt = t0 + tb - 3 + ii;
            xr[ii] = (gt >= 0)
                ? b2f(xcrb[((size_t)(b * L_) + gt) * ED_ + dbase + dls]) : 0.0f;
        }
        const float4 w = *reinterpret_cast<const float4*>(&cw[(dbase + dls) * 4]);
        const float cbv = cb[dbase + dls];
        #pragma unroll
        for (int k = 0; k < 8; ++k) {
            const float a = cbv + w.x * xr[k] + w.y * xr[k + 1]
                          + w.z * xr[k + 2] + w.w * xr[k + 3];
            sxc[tb + k][dls] = a / (1.0f + __expf(-a));
        }
    }
    // B/C staging
    #pragma unroll
    for (int e = 0; e < 4; ++e) {
        const int lin = tid + e * 256;
        bc[lin >> 5][lin & 31] = dbl[(row0 + (lin >> 5)) * 64 + 32 + (lin & 31)];
    }
    __syncthreads();

    const int dl = tid >> 2;
    const int ng = tid & 3;
    const int d  = dbase + dl;

    float Av[4];
    #pragma unroll
    for (int i = 0; i < 4; ++i) Av[i] = -expf(A_log[d * N_ + ng * 4 + i]);

    float h[4];
    float S = 0.0f;
    if (P3) {
        #pragma unroll
        for (int i = 0; i < 4; ++i)
            h[i] = hinit[((size_t)(b * SEG + seg) * N_ + ng * 4 + i) * ED_ + d];
    } else {
        #pragma unroll
        for (int i = 0; i < 4; ++i) h[i] = 0.0f;
    }
    const float Dd = P3 ? Dv[d] : 0.0f;

    #pragma unroll
    for (int t = 0; t < TS; ++t) {
        const float dvt = sdl[t][dl];
        const float xvt = sxc[t][dl];
        const float dx  = dvt * xvt;
        if (!P3) S += dvt;
        float ysum = 0.0f;
        #pragma unroll
        for (int i = 0; i < 4; ++i) {
            const float dA = __expf(dvt * Av[i]);
            h[i] = fmaf(dA, h[i], dx * bc[t][ng * 4 + i]);
            if (P3) ysum = fmaf(h[i], bc[t][16 + ng * 4 + i], ysum);
        }
        if (P3) {
            float y2 = ysum + __shfl_xor(ysum, 1, 64);
            float y4 = y2 + __shfl_xor(y2, 2, 64);
            if (ng == 0) {
                const float zv = b2f(zb[(row0 + t) * ED_ + d]);
                const float sz = zv / (1.0f + __expf(-zv));
                ybuf[(row0 + t) * ED_ + d] =
                    __float2bfloat16((y4 + Dd * xvt) * sz);
            }
        }
    }

    if (!P3) {
        #pragma unroll
        for (int i = 0; i < 4; ++i) {
            const size_t o = ((size_t)(b * SEG + seg) * N_ + ng * 4 + i) * ED_ + d;
            hend[o]  = h[i];
            pprod[o] = __expf(Av[i] * S);   // prod of exps = exp of sum
        }
    }
}

// Phase 2: parallel over (b,n,d) = 32768 threads, serial over SEG segments.
__global__ __launch_bounds__(256)
void ssm_combine_k(const float* __restrict__ hend, const float* __restrict__ pprod,
                   float* __restrict__ hinit)
{
    const int gid = blockIdx.x * 256 + threadIdx.x;
    const int d = gid & (ED_ - 1);
    const int n = (gid >> 10) & (N_ - 1);
    const int b = gid >> 14;
    size_t o = ((size_t)(b * SEG) * N_ + n) * ED_ + d;
    const size_t stride = (size_t)N_ * ED_;
    float h = 0.0f;
    #pragma unroll 8
    for (int s = 0; s < SEG; ++s) {
        hinit[o] = h;
        h = fmaf(pprod[o], h, hend[o]);
        o += stride;
    }
}

// ---------------------------------------------------------------------------
extern "C" void kernel_launch(void* const* d_in, const int* in_sizes, int n_in,
                              void* d_out, int out_size, void* d_ws, size_t ws_size,
                              hipStream_t stream)
{
    const float* x      = (const float*)d_in[0];
    const float* p_Wi   = (const float*)d_in[1];
    const float* p_bi   = (const float*)d_in[2];
    const float* p_bh   = (const float*)d_in[3];
    const float* p_Wo   = (const float*)d_in[4];
    const float* p_bo   = (const float*)d_in[5];
    const float* m_norm = (const float*)d_in[6];
    const float* m_inW  = (const float*)d_in[7];
    const float* m_cw   = (const float*)d_in[8];
    const float* m_cb   = (const float*)d_in[9];
    const float* m_xpW  = (const float*)d_in[10];
    const float* m_dtW  = (const float*)d_in[11];
    const float* m_dtb  = (const float*)d_in[12];
    const float* m_Alog = (const float*)d_in[13];
    const float* m_D    = (const float*)d_in[14];
    const float* m_outW = (const float*)d_in[15];
    const float* d_Wi   = (const float*)d_in[16];
    const float* d_bi   = (const float*)d_in[17];
    const float* d_bh   = (const float*)d_in[18];
    const float* d_Wo   = (const float*)d_in[19];
    const float* d_bo   = (const float*)d_in[20];
    float* out_f = (float*)d_out;
    float* ws = (float*)d_ws;

    // ---- workspace layout (floats), total ~19.0M floats = 76.1 MB ----
    float* OUT   = ws;                 //  2,097,152
    float* XCRB  = ws + 2097152;       //  2,097,152  (bf16 4096x1024; later CPART2)
    float* ZB    = ws + 4194304;       //  2,097,152  (bf16 4096x1024)
    float* DELB  = ws + 6291456;       //  2,097,152  (bf16 4096x1024)
    float* HEND  = ws + 8388608;       //  2,097,152  (first: xproj partials)
    float* PPROD = ws + 10485760;      //  2,097,152  (later: OUTb)
    float* HINIT = ws + 12582912;      //  2,097,152
    float* BF    = ws + 14680064;      //  2,097,152  bf16 activations
    float* WT    = ws + 16777216;      //  1,853,440  bf16 transposed weights
    float* DBL   = ws + 18630656;      //    262,144  (later: H2b)
    float* DBLF  = ws + 18892800;      //    131,072  bf16 dbl copy

    // aliases
    float* CPARTX = HEND;
    float* CPART2 = XCRB;
    __hip_bfloat16* Xb    = (__hip_bfloat16*)BF;
    __hip_bfloat16* H1b   = (__hip_bfloat16*)(BF + 262144);
    __hip_bfloat16* XNb   = (__hip_bfloat16*)BF;
    __hip_bfloat16* YB    = (__hip_bfloat16*)BF;
    __hip_bfloat16* H2b   = (__hip_bfloat16*)DBL;
    __hip_bfloat16* OUTb  = (__hip_bfloat16*)PPROD;
    __hip_bfloat16* DBLb  = (__hip_bfloat16*)DBLF;
    __hip_bfloat16* XCRbp = (__hip_bfloat16*)XCRB;
    __hip_bfloat16* Zbp   = (__hip_bfloat16*)ZB;
    __hip_bfloat16* DELbp = (__hip_bfloat16*)DELB;

    __hip_bfloat16* WTu     = (__hip_bfloat16*)WT;
    __hip_bfloat16* T_pWi   = WTu;            // [512][128]
    __hip_bfloat16* T_pWo   = WTu + 65536;    // [512][512]
    __hip_bfloat16* T_inW0  = WTu + 327680;   // [2048][512]
    __hip_bfloat16* T_inW1  = WTu + 1376256;
    __hip_bfloat16* T_xpW0  = WTu + 2424832;  // [64][1024]
    __hip_bfloat16* T_xpW1  = WTu + 2490368;
    __hip_bfloat16* T_outW0 = WTu + 2555904;  // [512][1024]
    __hip_bfloat16* T_outW1 = WTu + 3080192;
    __hip_bfloat16* T_dWi   = WTu + 3604480;  // [64][512]
    __hip_bfloat16* T_dtW0  = WTu + 3637248;  // [1024][32]
    __hip_bfloat16* T_dtW1  = WTu + 3670016;
    __hip_bfloat16* T_dWo   = WTu + 3702784;  // [64][64]

    const dim3 blk(256);

    // ---- all weight conversions + x cvt in one launch ----
    prep_k<<<dim3(PREP_BLOCKS), blk, 0, stream>>>(
        x, Xb, p_Wi, T_pWi, p_Wo, T_pWo, m_inW, T_inW0, T_inW1,
        m_xpW, T_xpW0, T_xpW1, m_outW, T_outW0, T_outW1,
        d_Wi, T_dWi, m_dtW, T_dtW0, T_dtW1, d_Wo, T_dWo);

    // ---- liquid1 ----
    mfma_gemm<128, 64, 64, 2, false><<<dim3(32, 8), blk, 0, stream>>>(
        (const ushort*)Xb, IN_, (const ushort*)T_pWi, IN_,
        nullptr, nullptr, nullptr,
        p_bi, p_bh, nullptr, H1b, H_, M_TOK, H_, IN_);
    mfma_gemm<128, 64, 64, 3, false><<<dim3(32, 8), blk, 0, stream>>>(
        (const ushort*)H1b, H_, (const ushort*)T_pWo, H_,
        nullptr, nullptr, nullptr,
        p_bo, nullptr, OUT, nullptr, H_, M_TOK, H_, H_);

    for (int l = 0; l < NL_; ++l) {
        const float* nw   = m_norm + l * H_;
        const float* cw   = m_cw   + l * ED_ * K_;
        const float* cb   = m_cb   + l * ED_;
        const float* dtb  = m_dtb  + l * ED_;
        const float* Alog = m_Alog + l * ED_ * N_;
        const float* Dv   = m_D    + l * ED_;
        const __hip_bfloat16* TinW  = l ? T_inW1  : T_inW0;
        const __hip_bfloat16* TxpW  = l ? T_xpW1  : T_xpW0;
        const __hip_bfloat16* ToutW = l ? T_outW1 : T_outW0;
        const __hip_bfloat16* TdtW  = l ? T_dtW1  : T_dtW0;

        rmsnorm_k<<<dim3(M_TOK), blk, 0, stream>>>(OUT, nw, XNb);
        // in_W: both halves in one dual launch, bf16 outputs
        mfma_gemm<128, 128, 64, 8, true><<<dim3(32, 8, 2), blk, 0, stream>>>(
            (const ushort*)XNb, H_, (const ushort*)TinW, H_,
            (const ushort*)(TinW + (size_t)ED_ * H_), nullptr, Zbp,
            nullptr, nullptr, nullptr, XCRbp, ED_, M_TOK, ED_, H_);
        // xproj with fused conv+silu A-staging (bf16 xcr input)
        xproj_gemm<<<dim3(32, 1, 8), blk, 0, stream>>>(
            (const ushort*)XCRbp, cw, cb, (const ushort*)TxpW, CPARTX);
        reduce_part_k<8, 0, false, false, 2><<<dim3(1024), blk, 0, stream>>>(
            CPARTX, nullptr, nullptr, DBL, DBLb, M_TOK * 64, 64);
        // delta = softplus(dbl @ dtW + dtb) via MFMA -> bf16
        mfma_gemm<128, 64, 32, 9, false><<<dim3(32, 16), blk, 0, stream>>>(
            (const ushort*)DBLb, 64, (const ushort*)TdtW, DR_,
            nullptr, nullptr, nullptr,
            dtb, nullptr, nullptr, DELbp, ED_, M_TOK, ED_, DR_);
        ssm_scan_k<false><<<dim3(2048), blk, 0, stream>>>(
            (const ushort*)DELbp, (const ushort*)XCRbp, DBL, cw, cb,
            nullptr, Alog, nullptr, HEND, PPROD, nullptr, nullptr);
        ssm_combine_k<<<dim3(128), blk, 0, stream>>>(HEND, PPROD, HINIT);
        ssm_scan_k<true><<<dim3(2048), blk, 0, stream>>>(
            (const ushort*)DELbp, (const ushort*)XCRbp, DBL, cw, cb,
            (const ushort*)Zbp, Alog, Dv, nullptr, nullptr, HINIT, YB);
        if (l == 0) {
            mfma_gemm<128, 64, 64, 1, false><<<dim3(32, 8), blk, 0, stream>>>(
                (const ushort*)YB, ED_, (const ushort*)ToutW, ED_,
                nullptr, nullptr, nullptr,
                nullptr, nullptr, OUT, nullptr, H_, M_TOK, H_, ED_);
        } else {
            mfma_gemm<128, 64, 64, 7, false><<<dim3(32, 8), blk, 0, stream>>>(
                (const ushort*)YB, ED_, (const ushort*)ToutW, ED_,
                nullptr, nullptr, nullptr,
                nullptr, nullptr, OUT, OUTb, H_, M_TOK, H_, ED_);
        }
    }

    // ---- liquid2 + final (fused v - tanh(v)) ----
    mfma_gemm<128, 64, 64, 4, false><<<dim3(32, 1, 8), blk, 0, stream>>>(
        (const ushort*)OUTb, H_, (const ushort*)T_dWi, H_,
        nullptr, nullptr, nullptr,
        nullptr, nullptr, CPART2, nullptr, 64, M_TOK, 64, H_ / 8);
    reduce_part_k<8, 1, true, true, 1><<<dim3(1024), blk, 0, stream>>>(
        CPART2, d_bi, d_bh, nullptr, H2b, M_TOK * 64, 64);
    mfma_gemm<128, 64, 64, 5, false><<<dim3(32, 1), blk, 0, stream>>>(
        (const ushort*)H2b, OUT_, (const ushort*)T_dWo, OUT_,
        nullptr, nullptr, nullptr,
        d_bo, nullptr, out_f, nullptr, OUT_, M_TOK, OUT_, OUT_);
}